// Round 1
// baseline (1266.161 us; speedup 1.0000x reference)
//
#include <hip/hip_runtime.h>

typedef __bf16 bf16_t;
typedef __attribute__((ext_vector_type(4))) __bf16 bf16x4;
typedef __attribute__((ext_vector_type(8))) __bf16 bf16x8;
typedef __attribute__((ext_vector_type(4))) float f32x4;

constexpr int BATCH = 16;
constexpr int LQ = 2048;
constexpr int LV = 2048;
constexpr int DIM = 1024;

constexpr int BM = 128, BN = 128, BK = 32;

// ---------------------------------------------------------------------------
// async global->LDS, 16 B per lane. LDS dest must be wave-uniform base + lane*16.
// ---------------------------------------------------------------------------
typedef __attribute__((address_space(1))) const unsigned int g_u32;
typedef __attribute__((address_space(3))) unsigned int l_u32;
__device__ __forceinline__ void glds16(const void* g, void* l) {
    __builtin_amdgcn_global_load_lds((g_u32*)g, (l_u32*)l, 16, 0, 0);
}

// ---------------------------------------------------------------------------
// prep: fp32 x -> hi = bf16(x), lo = bf16(x - hi)
// ---------------------------------------------------------------------------
__global__ __launch_bounds__(256)
void prep_kernel(const float4* __restrict__ src, bf16x4* __restrict__ hi,
                 bf16x4* __restrict__ lo, int n4) {
    int i = blockIdx.x * 256 + threadIdx.x;
    const int stride = gridDim.x * 256;
    for (; i < n4; i += stride) {
        const float4 x = src[i];
        const float xs[4] = {x.x, x.y, x.z, x.w};
        bf16x4 h, l;
#pragma unroll
        for (int e = 0; e < 4; ++e) {
            bf16_t hh = (bf16_t)xs[e];
            h[e] = hh;
            l[e] = (bf16_t)(xs[e] - (float)hh);
        }
        hi[i] = h;
        lo[i] = l;
    }
}

// ---------------------------------------------------------------------------
// V (B, LV, DIM) fp32 -> VT (B, DIM, LV) bf16.  64(k) x 32(d) tiles.
// ---------------------------------------------------------------------------
__global__ __launch_bounds__(256)
void vt_kernel(const float* __restrict__ V, bf16_t* __restrict__ VT) {
    __shared__ float tile[64][33];
    const int b  = blockIdx.z;
    const int k0 = blockIdx.x * 64;
    const int d0 = blockIdx.y * 32;
    const int tid = threadIdx.x;
    const float* Vb  = V  + (size_t)b * LV * DIM;
    bf16_t*      VTb = VT + (size_t)b * DIM * LV;

    const int r = tid >> 3;          // 0..31
    const int c = (tid & 7) * 4;     // 0..28
#pragma unroll
    for (int h = 0; h < 2; ++h) {
        const float4 x = *(const float4*)(Vb + (size_t)(k0 + r + h * 32) * DIM + d0 + c);
        tile[r + h * 32][c]     = x.x;
        tile[r + h * 32][c + 1] = x.y;
        tile[r + h * 32][c + 2] = x.z;
        tile[r + h * 32][c + 3] = x.w;
    }
    __syncthreads();
    const int dd = tid >> 3;         // 0..31
    const int kk = (tid & 7) * 8;    // 0..56
    bf16x8 o;
#pragma unroll
    for (int j = 0; j < 8; ++j) o[j] = (bf16_t)tile[kk + j][dd];
    *(bf16x8*)&VTb[(size_t)(d0 + dd) * LV + k0 + kk] = o;
}

// ---------------------------------------------------------------------------
// GEMM1 v2: S = Q.V^T, 3-term split-bf16.
// 256x256 tile, BK=32, 8 waves (2Mx4N), double-buffered 128 KB dynamic LDS,
// counted vmcnt(8) prefetch (never drains in main loop), 4 quadrant phases
// with s_setprio around MFMA clusters, 16B-chunk XOR swizzle
// (chunk ^= (row>>1)&3) applied on the global source + the LDS read side.
// ---------------------------------------------------------------------------
__global__ __launch_bounds__(512, 2)
void gemm1_v2(const bf16_t* __restrict__ Qh, const bf16_t* __restrict__ Ql,
              const bf16_t* __restrict__ Vh, const bf16_t* __restrict__ Vl,
              float* __restrict__ S) {
    extern __shared__ __align__(16) char smem[];
    bf16_t* lds = (bf16_t*)smem;   // [2 bufs][4 arrays: Ah Al Bh Bl][256][32]

    const int b  = blockIdx.z;
    const int m0 = blockIdx.y * 256;
    const int n0 = blockIdx.x * 256;
    const bf16_t* Qhb = Qh + (size_t)b * LQ * DIM;
    const bf16_t* Qlb = Ql + (size_t)b * LQ * DIM;
    const bf16_t* Vhb = Vh + (size_t)b * LV * DIM;
    const bf16_t* Vlb = Vl + (size_t)b * LV * DIM;
    float*        Sb  = S  + (size_t)b * LQ * LV;

    const int tid  = threadIdx.x;
    const int lane = tid & 63;
    const int wave = tid >> 6;
    const int wm   = (wave >> 2) * 128;   // 2 M-halves
    const int wn   = (wave & 3) * 64;     // 4 N-quarters
    const int l15  = lane & 15;
    const int quad = lane >> 4;
    const int swz  = (l15 >> 1) & 3;          // = (row>>1)&3 for row = 16*i + l15
    const int rq   = (quad ^ swz) * 8;        // swizzled k-chunk (elems)

    // staging: thread tid covers LDS chunk (row = tid>>2, chunk = tid&3) of a
    // 128-row half; source k-chunk is inverse-swizzled so the swizzled read
    // finds global chunk `quad` at LDS chunk quad^swz.
    const int srow = tid >> 2;                              // 0..127
    const int sseg = (((tid & 3) ^ ((tid >> 3) & 3)) * 8);  // elems
    const int sdst = tid * 8;                               // elems (= byte tid*16)

#define STAGE8(BUF, K0) do {                                                        \
    bf16_t* Lb = lds + (BUF) * 32768;                                               \
    glds16(Qhb + (size_t)(m0 + srow      ) * DIM + (K0) + sseg, Lb +         sdst); \
    glds16(Qhb + (size_t)(m0 + srow + 128) * DIM + (K0) + sseg, Lb +  4096 + sdst); \
    glds16(Qlb + (size_t)(m0 + srow      ) * DIM + (K0) + sseg, Lb +  8192 + sdst); \
    glds16(Qlb + (size_t)(m0 + srow + 128) * DIM + (K0) + sseg, Lb + 12288 + sdst); \
    glds16(Vhb + (size_t)(n0 + srow      ) * DIM + (K0) + sseg, Lb + 16384 + sdst); \
    glds16(Vhb + (size_t)(n0 + srow + 128) * DIM + (K0) + sseg, Lb + 20480 + sdst); \
    glds16(Vlb + (size_t)(n0 + srow      ) * DIM + (K0) + sseg, Lb + 24576 + sdst); \
    glds16(Vlb + (size_t)(n0 + srow + 128) * DIM + (K0) + sseg, Lb + 28672 + sdst); \
} while (0)

#define LOADA(QI) do {                                                       \
    _Pragma("unroll")                                                        \
    for (int ii = 0; ii < 4; ++ii) {                                         \
        const int row = wm + ((QI) * 4 + ii) * 16 + l15;                     \
        ah[ii] = *(const bf16x8*)(bufp +        row * 32 + rq);              \
        al[ii] = *(const bf16x8*)(bufp + 8192 + row * 32 + rq);              \
    }                                                                        \
} while (0)

#define LOADB(QJ) do {                                                       \
    _Pragma("unroll")                                                        \
    for (int jj = 0; jj < 2; ++jj) {                                         \
        const int row = wn + ((QJ) * 2 + jj) * 16 + l15;                     \
        bh[(QJ) * 2 + jj] = *(const bf16x8*)(bufp + 16384 + row * 32 + rq);  \
        bl[(QJ) * 2 + jj] = *(const bf16x8*)(bufp + 24576 + row * 32 + rq);  \
    }                                                                        \
} while (0)

#define MFMAQ(QI, QJ) do {                                                   \
    _Pragma("unroll")                                                        \
    for (int ii = 0; ii < 4; ++ii)                                           \
    _Pragma("unroll")                                                        \
    for (int jj = 0; jj < 2; ++jj)                                           \
        acc[(QI)*4+ii][(QJ)*2+jj] = __builtin_amdgcn_mfma_f32_16x16x32_bf16( \
            ah[ii], bh[(QJ)*2+jj], acc[(QI)*4+ii][(QJ)*2+jj], 0, 0, 0);      \
    _Pragma("unroll")                                                        \
    for (int ii = 0; ii < 4; ++ii)                                           \
    _Pragma("unroll")                                                        \
    for (int jj = 0; jj < 2; ++jj)                                           \
        acc[(QI)*4+ii][(QJ)*2+jj] = __builtin_amdgcn_mfma_f32_16x16x32_bf16( \
            ah[ii], bl[(QJ)*2+jj], acc[(QI)*4+ii][(QJ)*2+jj], 0, 0, 0);      \
    _Pragma("unroll")                                                        \
    for (int ii = 0; ii < 4; ++ii)                                           \
    _Pragma("unroll")                                                        \
    for (int jj = 0; jj < 2; ++jj)                                           \
        acc[(QI)*4+ii][(QJ)*2+jj] = __builtin_amdgcn_mfma_f32_16x16x32_bf16( \
            al[ii], bh[(QJ)*2+jj], acc[(QI)*4+ii][(QJ)*2+jj], 0, 0, 0);      \
} while (0)

    f32x4 acc[8][4];
#pragma unroll
    for (int i = 0; i < 8; ++i)
#pragma unroll
        for (int j = 0; j < 4; ++j) {
            f32x4 z = {0.f, 0.f, 0.f, 0.f};
            acc[i][j] = z;
        }

    bf16x8 ah[4], al[4], bh[4], bl[4];

    // prologue: stage tile 0 into buf 0 (no wait here; waited inside iter 0).
    STAGE8(0, 0);

    for (int t = 0; t < 32; ++t) {
        const bf16_t* bufp = lds + (t & 1) * 32768;
        if (t < 31) {
            STAGE8((t & 1) ^ 1, (t + 1) * 32);
            // 8 newest (tile t+1) may remain in flight; everything older
            // (tile t) must be complete.
            asm volatile("s_waitcnt vmcnt(8)" ::: "memory");
        } else {
            asm volatile("s_waitcnt vmcnt(0)" ::: "memory");
        }
        __builtin_amdgcn_s_barrier();   // tile t visible to all waves

        LOADA(0); LOADB(0);
        __builtin_amdgcn_s_barrier();
        __builtin_amdgcn_s_setprio(1); MFMAQ(0, 0); __builtin_amdgcn_s_setprio(0);
        __builtin_amdgcn_s_barrier();

        LOADB(1);
        __builtin_amdgcn_s_barrier();
        __builtin_amdgcn_s_setprio(1); MFMAQ(0, 1); __builtin_amdgcn_s_setprio(0);
        __builtin_amdgcn_s_barrier();

        LOADA(1);
        __builtin_amdgcn_s_barrier();
        __builtin_amdgcn_s_setprio(1); MFMAQ(1, 0); __builtin_amdgcn_s_setprio(0);
        __builtin_amdgcn_s_barrier();

        __builtin_amdgcn_s_setprio(1); MFMAQ(1, 1); __builtin_amdgcn_s_setprio(0);
        __builtin_amdgcn_s_barrier();
    }

#pragma unroll
    for (int i = 0; i < 8; ++i)
#pragma unroll
        for (int j = 0; j < 4; ++j)
#pragma unroll
            for (int r = 0; r < 4; ++r) {
                const int row = m0 + wm + i * 16 + quad * 4 + r;
                const int col = n0 + wn + j * 16 + l15;
                Sb[(size_t)row * LV + col] = acc[i][j][r];
            }

#undef STAGE8
#undef LOADA
#undef LOADB
#undef MFMAQ
}

// ---------------------------------------------------------------------------
// softmax (in-place fp32) + bf16 side copy for GEMM2
// ---------------------------------------------------------------------------
__global__ __launch_bounds__(256)
void softmax_b16(float* __restrict__ S, bf16_t* __restrict__ S16) {
    __shared__ float red[8];
    const size_t row = blockIdx.x;
    float* p = S + row * (size_t)LV;
    bf16_t* p16 = S16 + row * (size_t)LV;
    const int tid  = threadIdx.x;
    const int lane = tid & 63;
    const int wave = tid >> 6;

    float4 v0 = ((const float4*)p)[tid];
    float4 v1 = ((const float4*)p)[tid + 256];

    float m = fmaxf(fmaxf(fmaxf(v0.x, v0.y), fmaxf(v0.z, v0.w)),
                    fmaxf(fmaxf(v1.x, v1.y), fmaxf(v1.z, v1.w)));
#pragma unroll
    for (int off = 32; off > 0; off >>= 1) m = fmaxf(m, __shfl_xor(m, off));
    if (lane == 0) red[wave] = m;
    __syncthreads();
    m = fmaxf(fmaxf(red[0], red[1]), fmaxf(red[2], red[3]));

    float e0 = __expf(v0.x - m), e1 = __expf(v0.y - m);
    float e2 = __expf(v0.z - m), e3 = __expf(v0.w - m);
    float e4 = __expf(v1.x - m), e5 = __expf(v1.y - m);
    float e6 = __expf(v1.z - m), e7 = __expf(v1.w - m);

    float s = ((e0 + e1) + (e2 + e3)) + ((e4 + e5) + (e6 + e7));
#pragma unroll
    for (int off = 32; off > 0; off >>= 1) s += __shfl_xor(s, off);
    if (lane == 0) red[4 + wave] = s;
    __syncthreads();
    s = (red[4] + red[5]) + (red[6] + red[7]);

    const float inv = 1.0f / s;
    v0.x = e0 * inv; v0.y = e1 * inv; v0.z = e2 * inv; v0.w = e3 * inv;
    v1.x = e4 * inv; v1.y = e5 * inv; v1.z = e6 * inv; v1.w = e7 * inv;
    ((float4*)p)[tid]       = v0;
    ((float4*)p)[tid + 256] = v1;

    bf16x4 h0, h1;
    h0[0] = (bf16_t)v0.x; h0[1] = (bf16_t)v0.y; h0[2] = (bf16_t)v0.z; h0[3] = (bf16_t)v0.w;
    h1[0] = (bf16_t)v1.x; h1[1] = (bf16_t)v1.y; h1[2] = (bf16_t)v1.z; h1[3] = (bf16_t)v1.w;
    ((bf16x4*)p16)[tid]       = h0;
    ((bf16x4*)p16)[tid + 256] = h1;
}

// ---------------------------------------------------------------------------
// GEMM2 (glds): context = attn_bf16 . VT^T
// ---------------------------------------------------------------------------
__global__ __launch_bounds__(256, 3)
void gemm2_glds(const bf16_t* __restrict__ P16, const bf16_t* __restrict__ VT,
                float* __restrict__ C) {
    __shared__ __align__(16) bf16_t As[BM][BK];
    __shared__ __align__(16) bf16_t Bs[BN][BK];

    const int b  = blockIdx.z;
    const int m0 = blockIdx.y * BM;   // q
    const int n0 = blockIdx.x * BN;   // d
    const bf16_t* Pb = P16 + (size_t)b * LQ * LV;
    const bf16_t* Vb = VT  + (size_t)b * DIM * LV;
    float*        Cb = C   + (size_t)b * LQ * DIM;

    const int tid  = threadIdx.x;
    const int lane = tid & 63;
    const int wave = tid >> 6;
    const int wm   = (wave >> 1) * 64;
    const int wn   = (wave & 1) * 64;
    const int l15  = lane & 15;
    const int quad = lane >> 4;

    const int srow = tid >> 2;
    const int sseg = (tid & 3) * 8;

    f32x4 acc[4][4];
#pragma unroll
    for (int i = 0; i < 4; ++i)
#pragma unroll
        for (int j = 0; j < 4; ++j) {
            f32x4 z = {0.f, 0.f, 0.f, 0.f};
            acc[i][j] = z;
        }

    for (int k0 = 0; k0 < LV; k0 += BK) {
        glds16(Pb + (size_t)(m0 + srow) * LV + k0 + sseg,      &As[srow][sseg]);
        glds16(Pb + (size_t)(m0 + srow + 64) * LV + k0 + sseg, &As[srow + 64][sseg]);
        glds16(Vb + (size_t)(n0 + srow) * LV + k0 + sseg,      &Bs[srow][sseg]);
        glds16(Vb + (size_t)(n0 + srow + 64) * LV + k0 + sseg, &Bs[srow + 64][sseg]);
        __syncthreads();

        bf16x8 af[4], bfr[4];
#pragma unroll
        for (int i = 0; i < 4; ++i) {
            af[i]  = *(const bf16x8*)&As[wm + i * 16 + l15][quad * 8];
            bfr[i] = *(const bf16x8*)&Bs[wn + i * 16 + l15][quad * 8];
        }
#pragma unroll
        for (int i = 0; i < 4; ++i)
#pragma unroll
            for (int j = 0; j < 4; ++j)
                acc[i][j] = __builtin_amdgcn_mfma_f32_16x16x32_bf16(af[i], bfr[j], acc[i][j], 0, 0, 0);
        __syncthreads();
    }

#pragma unroll
    for (int i = 0; i < 4; ++i)
#pragma unroll
        for (int j = 0; j < 4; ++j)
#pragma unroll
            for (int r = 0; r < 4; ++r) {
                const int row = m0 + wm + i * 16 + quad * 4 + r;
                const int col = n0 + wn + j * 16 + l15;
                Cb[(size_t)row * DIM + col] = acc[i][j][r];
            }
}

// ===========================================================================
// Fallback tier (round-1 proven kernels) in case ws is too small.
// ===========================================================================
__global__ __launch_bounds__(256, 2)
void gemm1_fb(const float* __restrict__ Q, const float* __restrict__ V,
              float* __restrict__ S) {
    __shared__ __align__(16) bf16_t Ahi[BM][BK];
    __shared__ __align__(16) bf16_t Alo[BM][BK];
    __shared__ __align__(16) bf16_t Bhi[BN][BK];
    __shared__ __align__(16) bf16_t Blo[BN][BK];

    const int b  = blockIdx.z;
    const int m0 = blockIdx.y * BM;
    const int n0 = blockIdx.x * BN;
    const float* Qb = Q + (size_t)b * LQ * DIM;
    const float* Vb = V + (size_t)b * LV * DIM;
    float*       Sb = S + (size_t)b * LQ * LV;

    const int tid  = threadIdx.x;
    const int lane = tid & 63;
    const int wave = tid >> 6;
    const int wm   = (wave >> 1) * 64;
    const int wn   = (wave & 1) * 64;
    const int l15  = lane & 15;
    const int quad = lane >> 4;
    const int srow = tid >> 3;
    const int scol = (tid & 7) * 4;

    f32x4 acc[4][4];
#pragma unroll
    for (int i = 0; i < 4; ++i)
#pragma unroll
        for (int j = 0; j < 4; ++j) {
            f32x4 z = {0.f, 0.f, 0.f, 0.f};
            acc[i][j] = z;
        }

    for (int k0 = 0; k0 < DIM; k0 += BK) {
#pragma unroll
        for (int p = 0; p < 4; ++p) {
            const int r = p * 32 + srow;
            const float4 qa = *(const float4*)(Qb + (size_t)(m0 + r) * DIM + k0 + scol);
            const float4 va = *(const float4*)(Vb + (size_t)(n0 + r) * DIM + k0 + scol);
            const float qx[4] = {qa.x, qa.y, qa.z, qa.w};
            const float vx[4] = {va.x, va.y, va.z, va.w};
            bf16x4 qh, ql, vh, vl;
#pragma unroll
            for (int e = 0; e < 4; ++e) {
                bf16_t h = (bf16_t)qx[e];
                qh[e] = h; ql[e] = (bf16_t)(qx[e] - (float)h);
                bf16_t h2 = (bf16_t)vx[e];
                vh[e] = h2; vl[e] = (bf16_t)(vx[e] - (float)h2);
            }
            *(bf16x4*)&Ahi[r][scol] = qh;
            *(bf16x4*)&Alo[r][scol] = ql;
            *(bf16x4*)&Bhi[r][scol] = vh;
            *(bf16x4*)&Blo[r][scol] = vl;
        }
        __syncthreads();
        bf16x8 ah[4], al[4], bh[4], bl[4];
#pragma unroll
        for (int i = 0; i < 4; ++i) {
            ah[i] = *(const bf16x8*)&Ahi[wm + i * 16 + l15][quad * 8];
            al[i] = *(const bf16x8*)&Alo[wm + i * 16 + l15][quad * 8];
            bh[i] = *(const bf16x8*)&Bhi[wn + i * 16 + l15][quad * 8];
            bl[i] = *(const bf16x8*)&Blo[wn + i * 16 + l15][quad * 8];
        }
#pragma unroll
        for (int i = 0; i < 4; ++i)
#pragma unroll
            for (int j = 0; j < 4; ++j) {
                acc[i][j] = __builtin_amdgcn_mfma_f32_16x16x32_bf16(ah[i], bh[j], acc[i][j], 0, 0, 0);
                acc[i][j] = __builtin_amdgcn_mfma_f32_16x16x32_bf16(ah[i], bl[j], acc[i][j], 0, 0, 0);
                acc[i][j] = __builtin_amdgcn_mfma_f32_16x16x32_bf16(al[i], bh[j], acc[i][j], 0, 0, 0);
            }
        __syncthreads();
    }
#pragma unroll
    for (int i = 0; i < 4; ++i)
#pragma unroll
        for (int j = 0; j < 4; ++j)
#pragma unroll
            for (int r = 0; r < 4; ++r) {
                const int row = m0 + wm + i * 16 + quad * 4 + r;
                const int col = n0 + wn + j * 16 + l15;
                Sb[(size_t)row * LV + col] = acc[i][j][r];
            }
}

__global__ __launch_bounds__(256)
void softmax_fb(float* __restrict__ S) {
    __shared__ float red[8];
    const size_t row = blockIdx.x;
    float* p = S + row * (size_t)LV;
    const int tid  = threadIdx.x;
    const int lane = tid & 63;
    const int wave = tid >> 6;
    float4 v0 = ((const float4*)p)[tid];
    float4 v1 = ((const float4*)p)[tid + 256];
    float m = fmaxf(fmaxf(fmaxf(v0.x, v0.y), fmaxf(v0.z, v0.w)),
                    fmaxf(fmaxf(v1.x, v1.y), fmaxf(v1.z, v1.w)));
#pragma unroll
    for (int off = 32; off > 0; off >>= 1) m = fmaxf(m, __shfl_xor(m, off));
    if (lane == 0) red[wave] = m;
    __syncthreads();
    m = fmaxf(fmaxf(red[0], red[1]), fmaxf(red[2], red[3]));
    float e0 = __expf(v0.x - m), e1 = __expf(v0.y - m);
    float e2 = __expf(v0.z - m), e3 = __expf(v0.w - m);
    float e4 = __expf(v1.x - m), e5 = __expf(v1.y - m);
    float e6 = __expf(v1.z - m), e7 = __expf(v1.w - m);
    float s = ((e0 + e1) + (e2 + e3)) + ((e4 + e5) + (e6 + e7));
#pragma unroll
    for (int off = 32; off > 0; off >>= 1) s += __shfl_xor(s, off);
    if (lane == 0) red[4 + wave] = s;
    __syncthreads();
    s = (red[4] + red[5]) + (red[6] + red[7]);
    const float inv = 1.0f / s;
    v0.x = e0 * inv; v0.y = e1 * inv; v0.z = e2 * inv; v0.w = e3 * inv;
    v1.x = e4 * inv; v1.y = e5 * inv; v1.z = e6 * inv; v1.w = e7 * inv;
    ((float4*)p)[tid]       = v0;
    ((float4*)p)[tid + 256] = v1;
}

__global__ __launch_bounds__(256, 2)
void gemm2_fb(const float* __restrict__ P, const bf16_t* __restrict__ VT,
              float* __restrict__ C) {
    __shared__ __align__(16) bf16_t As[BM][BK];
    __shared__ __align__(16) bf16_t Bs[BN][BK];
    const int b  = blockIdx.z;
    const int m0 = blockIdx.y * BM;
    const int n0 = blockIdx.x * BN;
    const float*  Pb = P  + (size_t)b * LQ * LV;
    const bf16_t* Vb = VT + (size_t)b * DIM * LV;
    float*        Cb = C  + (size_t)b * LQ * DIM;
    const int tid  = threadIdx.x;
    const int lane = tid & 63;
    const int wave = tid >> 6;
    const int wm   = (wave >> 1) * 64;
    const int wn   = (wave & 1) * 64;
    const int l15  = lane & 15;
    const int quad = lane >> 4;
    const int arow = tid >> 3;
    const int acol = (tid & 7) * 4;
    const int brow = tid >> 2;
    const int bseg = (tid & 3) * 8;
    f32x4 acc[4][4];
#pragma unroll
    for (int i = 0; i < 4; ++i)
#pragma unroll
        for (int j = 0; j < 4; ++j) {
            f32x4 z = {0.f, 0.f, 0.f, 0.f};
            acc[i][j] = z;
        }
    for (int k0 = 0; k0 < LV; k0 += BK) {
#pragma unroll
        for (int p4 = 0; p4 < 4; ++p4) {
            const int r = p4 * 32 + arow;
            const float4 a = *(const float4*)(Pb + (size_t)(m0 + r) * LV + k0 + acol);
            bf16x4 hv;
            hv[0] = (bf16_t)a.x; hv[1] = (bf16_t)a.y;
            hv[2] = (bf16_t)a.z; hv[3] = (bf16_t)a.w;
            *(bf16x4*)&As[r][acol] = hv;
        }
#pragma unroll
        for (int p4 = 0; p4 < 2; ++p4) {
            const int r = p4 * 64 + brow;
            *(bf16x8*)&Bs[r][bseg] =
                *(const bf16x8*)(Vb + (size_t)(n0 + r) * LV + k0 + bseg);
        }
        __syncthreads();
        bf16x8 af[4], bfr[4];
#pragma unroll
        for (int i = 0; i < 4; ++i) {
            af[i]  = *(const bf16x8*)&As[wm + i * 16 + l15][quad * 8];
            bfr[i] = *(const bf16x8*)&Bs[wn + i * 16 + l15][quad * 8];
        }
#pragma unroll
        for (int i = 0; i < 4; ++i)
#pragma unroll
            for (int j = 0; j < 4; ++j)
                acc[i][j] = __builtin_amdgcn_mfma_f32_16x16x32_bf16(af[i], bfr[j], acc[i][j], 0, 0, 0);
        __syncthreads();
    }
#pragma unroll
    for (int i = 0; i < 4; ++i)
#pragma unroll
        for (int j = 0; j < 4; ++j)
#pragma unroll
            for (int r = 0; r < 4; ++r) {
                const int row = m0 + wm + i * 16 + quad * 4 + r;
                const int col = n0 + wn + j * 16 + l15;
                Cb[(size_t)row * DIM + col] = acc[i][j][r];
            }
}

// ---------------------------------------------------------------------------
extern "C" void kernel_launch(void* const* d_in, const int* in_sizes, int n_in,
                              void* d_out, int out_size, void* d_ws, size_t ws_size,
                              hipStream_t stream) {
    const float* Q = (const float*)d_in[0];
    const float* V = (const float*)d_in[1];
    float* ctx  = (float*)d_out;                       // B*LQ*DIM fp32
    float* attn = ctx + (size_t)BATCH * LQ * DIM;      // B*LQ*LV fp32
    char* ws = (char*)d_ws;

    const size_t EL = (size_t)BATCH * LQ * DIM;        // 33,554,432 elems
    const size_t SZ = EL * sizeof(bf16_t);             // 67,108,864 B

    if (ws_size >= 5 * SZ) {
        // Full tier: prep split + 8-phase 256^2 gemm1 + glds gemm2.
        static bool attr_set = false;
        if (!attr_set) {
            (void)hipFuncSetAttribute((const void*)gemm1_v2,
                                      hipFuncAttributeMaxDynamicSharedMemorySize,
                                      131072);
            attr_set = true;
        }
        bf16_t* Qh  = (bf16_t*)ws;
        bf16_t* Ql  = Qh + EL;
        bf16_t* Vh  = Ql + EL;
        bf16_t* Vl  = Vh + EL;
        bf16_t* VT  = (bf16_t*)(ws + 4 * SZ);
        bf16_t* P16 = (bf16_t*)ws;                     // aliases Qh/Ql after gemm1

        prep_kernel<<<4096, 256, 0, stream>>>((const float4*)Q, (bf16x4*)Qh, (bf16x4*)Ql, (int)(EL / 4));
        prep_kernel<<<4096, 256, 0, stream>>>((const float4*)V, (bf16x4*)Vh, (bf16x4*)Vl, (int)(EL / 4));
        vt_kernel<<<dim3(LV / 64, DIM / 32, BATCH), 256, 0, stream>>>(V, VT);
        gemm1_v2<<<dim3(LV / 256, LQ / 256, BATCH), 512, 131072, stream>>>(Qh, Ql, Vh, Vl, attn);
        softmax_b16<<<BATCH * LQ, 256, 0, stream>>>(attn, P16);
        gemm2_glds<<<dim3(DIM / BN, LQ / BM, BATCH), 256, 0, stream>>>(P16, VT, ctx);
    } else if (ws_size >= 3 * SZ) {
        // Mid tier: old gemm1, glds gemm2.
        bf16_t* VT  = (bf16_t*)ws;
        bf16_t* P16 = (bf16_t*)(ws + SZ);
        vt_kernel<<<dim3(LV / 64, DIM / 32, BATCH), 256, 0, stream>>>(V, VT);
        gemm1_fb<<<dim3(LV / BN, LQ / BM, BATCH), 256, 0, stream>>>(Q, V, attn);
        softmax_b16<<<BATCH * LQ, 256, 0, stream>>>(attn, P16);
        gemm2_glds<<<dim3(DIM / BN, LQ / BM, BATCH), 256, 0, stream>>>(P16, VT, ctx);
    } else {
        // Fallback: round-1 pipeline.
        bf16_t* VT = (bf16_t*)ws;
        vt_kernel<<<dim3(LV / 64, DIM / 32, BATCH), 256, 0, stream>>>(V, VT);
        gemm1_fb<<<dim3(LV / BN, LQ / BM, BATCH), 256, 0, stream>>>(Q, V, attn);
        softmax_fb<<<BATCH * LQ, 256, 0, stream>>>(attn);
        gemm2_fb<<<dim3(DIM / BN, LQ / BM, BATCH), 256, 0, stream>>>(attn, VT, ctx);
    }
}

// Round 2
// 1253.069 us; speedup vs baseline: 1.0104x; 1.0104x over previous
//
#include <hip/hip_runtime.h>

typedef __bf16 bf16_t;
typedef __attribute__((ext_vector_type(4))) __bf16 bf16x4;
typedef __attribute__((ext_vector_type(8))) __bf16 bf16x8;
typedef __attribute__((ext_vector_type(4))) float f32x4;

constexpr int BATCH = 16;
constexpr int LQ = 2048;
constexpr int LV = 2048;
constexpr int DIM = 1024;

constexpr int BM = 128, BN = 128, BK = 32;

// ---------------------------------------------------------------------------
// async global->LDS, 16 B per lane. LDS dest must be wave-uniform base + lane*16.
// ---------------------------------------------------------------------------
typedef __attribute__((address_space(1))) const unsigned int g_u32;
typedef __attribute__((address_space(3))) unsigned int l_u32;
__device__ __forceinline__ void glds16(const void* g, void* l) {
    __builtin_amdgcn_global_load_lds((g_u32*)g, (l_u32*)l, 16, 0, 0);
}

// ---------------------------------------------------------------------------
// prep: fp32 x -> hi = bf16(x), lo = bf16(x - hi)
// ---------------------------------------------------------------------------
__global__ __launch_bounds__(256)
void prep_kernel(const float4* __restrict__ src, bf16x4* __restrict__ hi,
                 bf16x4* __restrict__ lo, int n4) {
    int i = blockIdx.x * 256 + threadIdx.x;
    const int stride = gridDim.x * 256;
    for (; i < n4; i += stride) {
        const float4 x = src[i];
        const float xs[4] = {x.x, x.y, x.z, x.w};
        bf16x4 h, l;
#pragma unroll
        for (int e = 0; e < 4; ++e) {
            bf16_t hh = (bf16_t)xs[e];
            h[e] = hh;
            l[e] = (bf16_t)(xs[e] - (float)hh);
        }
        hi[i] = h;
        lo[i] = l;
    }
}

// ---------------------------------------------------------------------------
// V (B, LV, DIM) fp32 -> VT (B, DIM, LV) bf16.  64(k) x 32(d) tiles.
// ---------------------------------------------------------------------------
__global__ __launch_bounds__(256)
void vt_kernel(const float* __restrict__ V, bf16_t* __restrict__ VT) {
    __shared__ float tile[64][33];
    const int b  = blockIdx.z;
    const int k0 = blockIdx.x * 64;
    const int d0 = blockIdx.y * 32;
    const int tid = threadIdx.x;
    const float* Vb  = V  + (size_t)b * LV * DIM;
    bf16_t*      VTb = VT + (size_t)b * DIM * LV;

    const int r = tid >> 3;          // 0..31
    const int c = (tid & 7) * 4;     // 0..28
#pragma unroll
    for (int h = 0; h < 2; ++h) {
        const float4 x = *(const float4*)(Vb + (size_t)(k0 + r + h * 32) * DIM + d0 + c);
        tile[r + h * 32][c]     = x.x;
        tile[r + h * 32][c + 1] = x.y;
        tile[r + h * 32][c + 2] = x.z;
        tile[r + h * 32][c + 3] = x.w;
    }
    __syncthreads();
    const int dd = tid >> 3;         // 0..31
    const int kk = (tid & 7) * 8;    // 0..56
    bf16x8 o;
#pragma unroll
    for (int j = 0; j < 8; ++j) o[j] = (bf16_t)tile[kk + j][dd];
    *(bf16x8*)&VTb[(size_t)(d0 + dd) * LV + k0 + kk] = o;
}

// ---------------------------------------------------------------------------
// GEMM1 v3: S = Q.V^T, 3-term split-bf16.
// 256x256 tile, BK=32, 8 waves (2Mx4N), double-buffered 128 KB dynamic LDS,
// counted vmcnt(8) prefetch, 16B-chunk XOR swizzle (zero bank conflicts,
// verified r1).  v3 change: ONE compute region per K-step between TWO
// barriers — ds_reads and MFMAs co-scheduled by the compiler's fine-grained
// lgkmcnt, so LDS reads of one wave overlap MFMA of another (v2's 9-barrier
// lockstep serialized LDS bursts against MFMA bursts: 7.8k cyc/K-step vs
// the 3.7k MFMA floor).
// ---------------------------------------------------------------------------
__global__ __launch_bounds__(512, 2)
void gemm1_v3(const bf16_t* __restrict__ Qh, const bf16_t* __restrict__ Ql,
              const bf16_t* __restrict__ Vh, const bf16_t* __restrict__ Vl,
              float* __restrict__ S) {
    extern __shared__ __align__(16) char smem[];
    bf16_t* lds = (bf16_t*)smem;   // [2 bufs][4 arrays: Ah Al Bh Bl][256][32]

    const int b  = blockIdx.z;
    const int m0 = blockIdx.y * 256;
    const int n0 = blockIdx.x * 256;
    const bf16_t* Qhb = Qh + (size_t)b * LQ * DIM;
    const bf16_t* Qlb = Ql + (size_t)b * LQ * DIM;
    const bf16_t* Vhb = Vh + (size_t)b * LV * DIM;
    const bf16_t* Vlb = Vl + (size_t)b * LV * DIM;
    float*        Sb  = S  + (size_t)b * LQ * LV;

    const int tid  = threadIdx.x;
    const int lane = tid & 63;
    const int wave = tid >> 6;
    const int wm   = (wave >> 2) * 128;   // 2 M-halves
    const int wn   = (wave & 3) * 64;     // 4 N-quarters
    const int l15  = lane & 15;
    const int quad = lane >> 4;
    const int swz  = (l15 >> 1) & 3;          // = (row>>1)&3 for row = 16*i + l15
    const int rq   = (quad ^ swz) * 8;        // swizzled k-chunk (elems)

    // staging: thread tid covers LDS chunk (row = tid>>2, chunk = tid&3) of a
    // 128-row half; source k-chunk is inverse-swizzled so the swizzled read
    // finds global chunk `quad` at LDS chunk quad^swz.
    const int srow = tid >> 2;                              // 0..127
    const int sseg = (((tid & 3) ^ ((tid >> 3) & 3)) * 8);  // elems
    const int sdst = tid * 8;                               // elems (= byte tid*16)

#define STAGE8(BUF, K0) do {                                                        \
    bf16_t* Lb = lds + (BUF) * 32768;                                               \
    glds16(Qhb + (size_t)(m0 + srow      ) * DIM + (K0) + sseg, Lb +         sdst); \
    glds16(Qhb + (size_t)(m0 + srow + 128) * DIM + (K0) + sseg, Lb +  4096 + sdst); \
    glds16(Qlb + (size_t)(m0 + srow      ) * DIM + (K0) + sseg, Lb +  8192 + sdst); \
    glds16(Qlb + (size_t)(m0 + srow + 128) * DIM + (K0) + sseg, Lb + 12288 + sdst); \
    glds16(Vhb + (size_t)(n0 + srow      ) * DIM + (K0) + sseg, Lb + 16384 + sdst); \
    glds16(Vhb + (size_t)(n0 + srow + 128) * DIM + (K0) + sseg, Lb + 20480 + sdst); \
    glds16(Vlb + (size_t)(n0 + srow      ) * DIM + (K0) + sseg, Lb + 24576 + sdst); \
    glds16(Vlb + (size_t)(n0 + srow + 128) * DIM + (K0) + sseg, Lb + 28672 + sdst); \
} while (0)

#define LOADA(QI) do {                                                       \
    _Pragma("unroll")                                                        \
    for (int ii = 0; ii < 4; ++ii) {                                         \
        const int row = wm + ((QI) * 4 + ii) * 16 + l15;                     \
        ah[ii] = *(const bf16x8*)(bufp +        row * 32 + rq);              \
        al[ii] = *(const bf16x8*)(bufp + 8192 + row * 32 + rq);              \
    }                                                                        \
} while (0)

#define LOADB(QJ) do {                                                       \
    _Pragma("unroll")                                                        \
    for (int jj = 0; jj < 2; ++jj) {                                         \
        const int row = wn + ((QJ) * 2 + jj) * 16 + l15;                     \
        bh[(QJ) * 2 + jj] = *(const bf16x8*)(bufp + 16384 + row * 32 + rq);  \
        bl[(QJ) * 2 + jj] = *(const bf16x8*)(bufp + 24576 + row * 32 + rq);  \
    }                                                                        \
} while (0)

#define MFMAQ(QI, QJ) do {                                                   \
    _Pragma("unroll")                                                        \
    for (int ii = 0; ii < 4; ++ii)                                           \
    _Pragma("unroll")                                                        \
    for (int jj = 0; jj < 2; ++jj)                                           \
        acc[(QI)*4+ii][(QJ)*2+jj] = __builtin_amdgcn_mfma_f32_16x16x32_bf16( \
            ah[ii], bh[(QJ)*2+jj], acc[(QI)*4+ii][(QJ)*2+jj], 0, 0, 0);      \
    _Pragma("unroll")                                                        \
    for (int ii = 0; ii < 4; ++ii)                                           \
    _Pragma("unroll")                                                        \
    for (int jj = 0; jj < 2; ++jj)                                           \
        acc[(QI)*4+ii][(QJ)*2+jj] = __builtin_amdgcn_mfma_f32_16x16x32_bf16( \
            ah[ii], bl[(QJ)*2+jj], acc[(QI)*4+ii][(QJ)*2+jj], 0, 0, 0);      \
    _Pragma("unroll")                                                        \
    for (int ii = 0; ii < 4; ++ii)                                           \
    _Pragma("unroll")                                                        \
    for (int jj = 0; jj < 2; ++jj)                                           \
        acc[(QI)*4+ii][(QJ)*2+jj] = __builtin_amdgcn_mfma_f32_16x16x32_bf16( \
            al[ii], bh[(QJ)*2+jj], acc[(QI)*4+ii][(QJ)*2+jj], 0, 0, 0);      \
} while (0)

    f32x4 acc[8][4];
#pragma unroll
    for (int i = 0; i < 8; ++i)
#pragma unroll
        for (int j = 0; j < 4; ++j) {
            f32x4 z = {0.f, 0.f, 0.f, 0.f};
            acc[i][j] = z;
        }

    bf16x8 ah[4], al[4], bh[4], bl[4];

    // prologue: stage tile 0 into buf 0 (waited inside iter 0).
    STAGE8(0, 0);

    for (int t = 0; t < 32; ++t) {
        const bf16_t* bufp = lds + (t & 1) * 32768;
        if (t < 31) {
            STAGE8((t & 1) ^ 1, (t + 1) * 32);
            // 8 newest (tile t+1) may remain in flight; everything older
            // (tile t) must be complete.
            asm volatile("s_waitcnt vmcnt(8)" ::: "memory");
        } else {
            asm volatile("s_waitcnt vmcnt(0)" ::: "memory");
        }
        __builtin_amdgcn_s_barrier();   // tile t visible to all waves

        // One region: compiler interleaves ds_reads with MFMAs via fine
        // lgkmcnt; waves desync between the two barriers so one wave's LDS
        // reads overlap another's MFMA.  LOADA(1) hides under MFMAQ(0,*).
        __builtin_amdgcn_s_setprio(1);
        LOADA(0); LOADB(0); LOADB(1);
        MFMAQ(0, 0); MFMAQ(0, 1);
        LOADA(1);
        MFMAQ(1, 0); MFMAQ(1, 1);
        __builtin_amdgcn_s_setprio(0);

        // All ds_reads were consumed by the MFMAs above (compiler-inserted
        // lgkmcnt waits), so crossing this barrier means this wave is done
        // reading buf[t&1]; next iter's STAGE may overwrite it.
        __builtin_amdgcn_s_barrier();
    }

#pragma unroll
    for (int i = 0; i < 8; ++i)
#pragma unroll
        for (int j = 0; j < 4; ++j)
#pragma unroll
            for (int r = 0; r < 4; ++r) {
                const int row = m0 + wm + i * 16 + quad * 4 + r;
                const int col = n0 + wn + j * 16 + l15;
                Sb[(size_t)row * LV + col] = acc[i][j][r];
            }

#undef STAGE8
#undef LOADA
#undef LOADB
#undef MFMAQ
}

// ---------------------------------------------------------------------------
// softmax (in-place fp32) + bf16 side copy for GEMM2
// ---------------------------------------------------------------------------
__global__ __launch_bounds__(256)
void softmax_b16(float* __restrict__ S, bf16_t* __restrict__ S16) {
    __shared__ float red[8];
    const size_t row = blockIdx.x;
    float* p = S + row * (size_t)LV;
    bf16_t* p16 = S16 + row * (size_t)LV;
    const int tid  = threadIdx.x;
    const int lane = tid & 63;
    const int wave = tid >> 6;

    float4 v0 = ((const float4*)p)[tid];
    float4 v1 = ((const float4*)p)[tid + 256];

    float m = fmaxf(fmaxf(fmaxf(v0.x, v0.y), fmaxf(v0.z, v0.w)),
                    fmaxf(fmaxf(v1.x, v1.y), fmaxf(v1.z, v1.w)));
#pragma unroll
    for (int off = 32; off > 0; off >>= 1) m = fmaxf(m, __shfl_xor(m, off));
    if (lane == 0) red[wave] = m;
    __syncthreads();
    m = fmaxf(fmaxf(red[0], red[1]), fmaxf(red[2], red[3]));

    float e0 = __expf(v0.x - m), e1 = __expf(v0.y - m);
    float e2 = __expf(v0.z - m), e3 = __expf(v0.w - m);
    float e4 = __expf(v1.x - m), e5 = __expf(v1.y - m);
    float e6 = __expf(v1.z - m), e7 = __expf(v1.w - m);

    float s = ((e0 + e1) + (e2 + e3)) + ((e4 + e5) + (e6 + e7));
#pragma unroll
    for (int off = 32; off > 0; off >>= 1) s += __shfl_xor(s, off);
    if (lane == 0) red[4 + wave] = s;
    __syncthreads();
    s = (red[4] + red[5]) + (red[6] + red[7]);

    const float inv = 1.0f / s;
    v0.x = e0 * inv; v0.y = e1 * inv; v0.z = e2 * inv; v0.w = e3 * inv;
    v1.x = e4 * inv; v1.y = e5 * inv; v1.z = e6 * inv; v1.w = e7 * inv;
    ((float4*)p)[tid]       = v0;
    ((float4*)p)[tid + 256] = v1;

    bf16x4 h0, h1;
    h0[0] = (bf16_t)v0.x; h0[1] = (bf16_t)v0.y; h0[2] = (bf16_t)v0.z; h0[3] = (bf16_t)v0.w;
    h1[0] = (bf16_t)v1.x; h1[1] = (bf16_t)v1.y; h1[2] = (bf16_t)v1.z; h1[3] = (bf16_t)v1.w;
    ((bf16x4*)p16)[tid]       = h0;
    ((bf16x4*)p16)[tid + 256] = h1;
}

// ---------------------------------------------------------------------------
// GEMM2 (glds): context = attn_bf16 . VT^T
// ---------------------------------------------------------------------------
__global__ __launch_bounds__(256, 3)
void gemm2_glds(const bf16_t* __restrict__ P16, const bf16_t* __restrict__ VT,
                float* __restrict__ C) {
    __shared__ __align__(16) bf16_t As[BM][BK];
    __shared__ __align__(16) bf16_t Bs[BN][BK];

    const int b  = blockIdx.z;
    const int m0 = blockIdx.y * BM;   // q
    const int n0 = blockIdx.x * BN;   // d
    const bf16_t* Pb = P16 + (size_t)b * LQ * LV;
    const bf16_t* Vb = VT  + (size_t)b * DIM * LV;
    float*        Cb = C   + (size_t)b * LQ * DIM;

    const int tid  = threadIdx.x;
    const int lane = tid & 63;
    const int wave = tid >> 6;
    const int wm   = (wave >> 1) * 64;
    const int wn   = (wave & 1) * 64;
    const int l15  = lane & 15;
    const int quad = lane >> 4;

    const int srow = tid >> 2;
    const int sseg = (tid & 3) * 8;

    f32x4 acc[4][4];
#pragma unroll
    for (int i = 0; i < 4; ++i)
#pragma unroll
        for (int j = 0; j < 4; ++j) {
            f32x4 z = {0.f, 0.f, 0.f, 0.f};
            acc[i][j] = z;
        }

    for (int k0 = 0; k0 < LV; k0 += BK) {
        glds16(Pb + (size_t)(m0 + srow) * LV + k0 + sseg,      &As[srow][sseg]);
        glds16(Pb + (size_t)(m0 + srow + 64) * LV + k0 + sseg, &As[srow + 64][sseg]);
        glds16(Vb + (size_t)(n0 + srow) * LV + k0 + sseg,      &Bs[srow][sseg]);
        glds16(Vb + (size_t)(n0 + srow + 64) * LV + k0 + sseg, &Bs[srow + 64][sseg]);
        __syncthreads();

        bf16x8 af[4], bfr[4];
#pragma unroll
        for (int i = 0; i < 4; ++i) {
            af[i]  = *(const bf16x8*)&As[wm + i * 16 + l15][quad * 8];
            bfr[i] = *(const bf16x8*)&Bs[wn + i * 16 + l15][quad * 8];
        }
#pragma unroll
        for (int i = 0; i < 4; ++i)
#pragma unroll
            for (int j = 0; j < 4; ++j)
                acc[i][j] = __builtin_amdgcn_mfma_f32_16x16x32_bf16(af[i], bfr[j], acc[i][j], 0, 0, 0);
        __syncthreads();
    }

#pragma unroll
    for (int i = 0; i < 4; ++i)
#pragma unroll
        for (int j = 0; j < 4; ++j)
#pragma unroll
            for (int r = 0; r < 4; ++r) {
                const int row = m0 + wm + i * 16 + quad * 4 + r;
                const int col = n0 + wn + j * 16 + l15;
                Cb[(size_t)row * DIM + col] = acc[i][j][r];
            }
}

// ===========================================================================
// Fallback tier (round-1 proven kernels) in case ws is too small.
// ===========================================================================
__global__ __launch_bounds__(256, 2)
void gemm1_fb(const float* __restrict__ Q, const float* __restrict__ V,
              float* __restrict__ S) {
    __shared__ __align__(16) bf16_t Ahi[BM][BK];
    __shared__ __align__(16) bf16_t Alo[BM][BK];
    __shared__ __align__(16) bf16_t Bhi[BN][BK];
    __shared__ __align__(16) bf16_t Blo[BN][BK];

    const int b  = blockIdx.z;
    const int m0 = blockIdx.y * BM;
    const int n0 = blockIdx.x * BN;
    const float* Qb = Q + (size_t)b * LQ * DIM;
    const float* Vb = V + (size_t)b * LV * DIM;
    float*       Sb = S + (size_t)b * LQ * LV;

    const int tid  = threadIdx.x;
    const int lane = tid & 63;
    const int wave = tid >> 6;
    const int wm   = (wave >> 1) * 64;
    const int wn   = (wave & 1) * 64;
    const int l15  = lane & 15;
    const int quad = lane >> 4;
    const int srow = tid >> 3;
    const int scol = (tid & 7) * 4;

    f32x4 acc[4][4];
#pragma unroll
    for (int i = 0; i < 4; ++i)
#pragma unroll
        for (int j = 0; j < 4; ++j) {
            f32x4 z = {0.f, 0.f, 0.f, 0.f};
            acc[i][j] = z;
        }

    for (int k0 = 0; k0 < DIM; k0 += BK) {
#pragma unroll
        for (int p = 0; p < 4; ++p) {
            const int r = p * 32 + srow;
            const float4 qa = *(const float4*)(Qb + (size_t)(m0 + r) * DIM + k0 + scol);
            const float4 va = *(const float4*)(Vb + (size_t)(n0 + r) * DIM + k0 + scol);
            const float qx[4] = {qa.x, qa.y, qa.z, qa.w};
            const float vx[4] = {va.x, va.y, va.z, va.w};
            bf16x4 qh, ql, vh, vl;
#pragma unroll
            for (int e = 0; e < 4; ++e) {
                bf16_t h = (bf16_t)qx[e];
                qh[e] = h; ql[e] = (bf16_t)(qx[e] - (float)h);
                bf16_t h2 = (bf16_t)vx[e];
                vh[e] = h2; vl[e] = (bf16_t)(vx[e] - (float)h2);
            }
            *(bf16x4*)&Ahi[r][scol] = qh;
            *(bf16x4*)&Alo[r][scol] = ql;
            *(bf16x4*)&Bhi[r][scol] = vh;
            *(bf16x4*)&Blo[r][scol] = vl;
        }
        __syncthreads();
        bf16x8 ah[4], al[4], bh[4], bl[4];
#pragma unroll
        for (int i = 0; i < 4; ++i) {
            ah[i] = *(const bf16x8*)&Ahi[wm + i * 16 + l15][quad * 8];
            al[i] = *(const bf16x8*)&Alo[wm + i * 16 + l15][quad * 8];
            bh[i] = *(const bf16x8*)&Bhi[wn + i * 16 + l15][quad * 8];
            bl[i] = *(const bf16x8*)&Blo[wn + i * 16 + l15][quad * 8];
        }
#pragma unroll
        for (int i = 0; i < 4; ++i)
#pragma unroll
            for (int j = 0; j < 4; ++j) {
                acc[i][j] = __builtin_amdgcn_mfma_f32_16x16x32_bf16(ah[i], bh[j], acc[i][j], 0, 0, 0);
                acc[i][j] = __builtin_amdgcn_mfma_f32_16x16x32_bf16(ah[i], bl[j], acc[i][j], 0, 0, 0);
                acc[i][j] = __builtin_amdgcn_mfma_f32_16x16x32_bf16(al[i], bh[j], acc[i][j], 0, 0, 0);
            }
        __syncthreads();
    }
#pragma unroll
    for (int i = 0; i < 4; ++i)
#pragma unroll
        for (int j = 0; j < 4; ++j)
#pragma unroll
            for (int r = 0; r < 4; ++r) {
                const int row = m0 + wm + i * 16 + quad * 4 + r;
                const int col = n0 + wn + j * 16 + l15;
                Sb[(size_t)row * LV + col] = acc[i][j][r];
            }
}

__global__ __launch_bounds__(256)
void softmax_fb(float* __restrict__ S) {
    __shared__ float red[8];
    const size_t row = blockIdx.x;
    float* p = S + row * (size_t)LV;
    const int tid  = threadIdx.x;
    const int lane = tid & 63;
    const int wave = tid >> 6;
    float4 v0 = ((const float4*)p)[tid];
    float4 v1 = ((const float4*)p)[tid + 256];
    float m = fmaxf(fmaxf(fmaxf(v0.x, v0.y), fmaxf(v0.z, v0.w)),
                    fmaxf(fmaxf(v1.x, v1.y), fmaxf(v1.z, v1.w)));
#pragma unroll
    for (int off = 32; off > 0; off >>= 1) m = fmaxf(m, __shfl_xor(m, off));
    if (lane == 0) red[wave] = m;
    __syncthreads();
    m = fmaxf(fmaxf(red[0], red[1]), fmaxf(red[2], red[3]));
    float e0 = __expf(v0.x - m), e1 = __expf(v0.y - m);
    float e2 = __expf(v0.z - m), e3 = __expf(v0.w - m);
    float e4 = __expf(v1.x - m), e5 = __expf(v1.y - m);
    float e6 = __expf(v1.z - m), e7 = __expf(v1.w - m);
    float s = ((e0 + e1) + (e2 + e3)) + ((e4 + e5) + (e6 + e7));
#pragma unroll
    for (int off = 32; off > 0; off >>= 1) s += __shfl_xor(s, off);
    if (lane == 0) red[4 + wave] = s;
    __syncthreads();
    s = (red[4] + red[5]) + (red[6] + red[7]);
    const float inv = 1.0f / s;
    v0.x = e0 * inv; v0.y = e1 * inv; v0.z = e2 * inv; v0.w = e3 * inv;
    v1.x = e4 * inv; v1.y = e5 * inv; v1.z = e6 * inv; v1.w = e7 * inv;
    ((float4*)p)[tid]       = v0;
    ((float4*)p)[tid + 256] = v1;
}

__global__ __launch_bounds__(256, 2)
void gemm2_fb(const float* __restrict__ P, const bf16_t* __restrict__ VT,
              float* __restrict__ C) {
    __shared__ __align__(16) bf16_t As[BM][BK];
    __shared__ __align__(16) bf16_t Bs[BN][BK];
    const int b  = blockIdx.z;
    const int m0 = blockIdx.y * BM;
    const int n0 = blockIdx.x * BN;
    const float*  Pb = P  + (size_t)b * LQ * LV;
    const bf16_t* Vb = VT + (size_t)b * DIM * LV;
    float*        Cb = C  + (size_t)b * LQ * DIM;
    const int tid  = threadIdx.x;
    const int lane = tid & 63;
    const int wave = tid >> 6;
    const int wm   = (wave >> 1) * 64;
    const int wn   = (wave & 1) * 64;
    const int l15  = lane & 15;
    const int quad = lane >> 4;
    const int arow = tid >> 3;
    const int acol = (tid & 7) * 4;
    const int brow = tid >> 2;
    const int bseg = (tid & 3) * 8;
    f32x4 acc[4][4];
#pragma unroll
    for (int i = 0; i < 4; ++i)
#pragma unroll
        for (int j = 0; j < 4; ++j) {
            f32x4 z = {0.f, 0.f, 0.f, 0.f};
            acc[i][j] = z;
        }
    for (int k0 = 0; k0 < LV; k0 += BK) {
#pragma unroll
        for (int p4 = 0; p4 < 4; ++p4) {
            const int r = p4 * 32 + arow;
            const float4 a = *(const float4*)(Pb + (size_t)(m0 + r) * LV + k0 + acol);
            bf16x4 hv;
            hv[0] = (bf16_t)a.x; hv[1] = (bf16_t)a.y;
            hv[2] = (bf16_t)a.z; hv[3] = (bf16_t)a.w;
            *(bf16x4*)&As[r][acol] = hv;
        }
#pragma unroll
        for (int p4 = 0; p4 < 2; ++p4) {
            const int r = p4 * 64 + brow;
            *(bf16x8*)&Bs[r][bseg] =
                *(const bf16x8*)(Vb + (size_t)(n0 + r) * LV + k0 + bseg);
        }
        __syncthreads();
        bf16x8 af[4], bfr[4];
#pragma unroll
        for (int i = 0; i < 4; ++i) {
            af[i]  = *(const bf16x8*)&As[wm + i * 16 + l15][quad * 8];
            bfr[i] = *(const bf16x8*)&Bs[wn + i * 16 + l15][quad * 8];
        }
#pragma unroll
        for (int i = 0; i < 4; ++i)
#pragma unroll
            for (int j = 0; j < 4; ++j)
                acc[i][j] = __builtin_amdgcn_mfma_f32_16x16x32_bf16(af[i], bfr[j], acc[i][j], 0, 0, 0);
        __syncthreads();
    }
#pragma unroll
    for (int i = 0; i < 4; ++i)
#pragma unroll
        for (int j = 0; j < 4; ++j)
#pragma unroll
            for (int r = 0; r < 4; ++r) {
                const int row = m0 + wm + i * 16 + quad * 4 + r;
                const int col = n0 + wn + j * 16 + l15;
                Cb[(size_t)row * DIM + col] = acc[i][j][r];
            }
}

// ---------------------------------------------------------------------------
extern "C" void kernel_launch(void* const* d_in, const int* in_sizes, int n_in,
                              void* d_out, int out_size, void* d_ws, size_t ws_size,
                              hipStream_t stream) {
    const float* Q = (const float*)d_in[0];
    const float* V = (const float*)d_in[1];
    float* ctx  = (float*)d_out;                       // B*LQ*DIM fp32
    float* attn = ctx + (size_t)BATCH * LQ * DIM;      // B*LQ*LV fp32
    char* ws = (char*)d_ws;

    const size_t EL = (size_t)BATCH * LQ * DIM;        // 33,554,432 elems
    const size_t SZ = EL * sizeof(bf16_t);             // 67,108,864 B

    if (ws_size >= 5 * SZ) {
        // Full tier: prep split + 2-barrier 256^2 gemm1 + glds gemm2.
        static bool attr_set = false;
        if (!attr_set) {
            (void)hipFuncSetAttribute((const void*)gemm1_v3,
                                      hipFuncAttributeMaxDynamicSharedMemorySize,
                                      131072);
            attr_set = true;
        }
        bf16_t* Qh  = (bf16_t*)ws;
        bf16_t* Ql  = Qh + EL;
        bf16_t* Vh  = Ql + EL;
        bf16_t* Vl  = Vh + EL;
        bf16_t* VT  = (bf16_t*)(ws + 4 * SZ);
        bf16_t* P16 = (bf16_t*)ws;                     // aliases Qh/Ql after gemm1

        prep_kernel<<<4096, 256, 0, stream>>>((const float4*)Q, (bf16x4*)Qh, (bf16x4*)Ql, (int)(EL / 4));
        prep_kernel<<<4096, 256, 0, stream>>>((const float4*)V, (bf16x4*)Vh, (bf16x4*)Vl, (int)(EL / 4));
        vt_kernel<<<dim3(LV / 64, DIM / 32, BATCH), 256, 0, stream>>>(V, VT);
        gemm1_v3<<<dim3(LV / 256, LQ / 256, BATCH), 512, 131072, stream>>>(Qh, Ql, Vh, Vl, attn);
        softmax_b16<<<BATCH * LQ, 256, 0, stream>>>(attn, P16);
        gemm2_glds<<<dim3(DIM / BN, LQ / BM, BATCH), 256, 0, stream>>>(P16, VT, ctx);
    } else if (ws_size >= 3 * SZ) {
        // Mid tier: old gemm1, glds gemm2.
        bf16_t* VT  = (bf16_t*)ws;
        bf16_t* P16 = (bf16_t*)(ws + SZ);
        vt_kernel<<<dim3(LV / 64, DIM / 32, BATCH), 256, 0, stream>>>(V, VT);
        gemm1_fb<<<dim3(LV / BN, LQ / BM, BATCH), 256, 0, stream>>>(Q, V, attn);
        softmax_b16<<<BATCH * LQ, 256, 0, stream>>>(attn, P16);
        gemm2_glds<<<dim3(DIM / BN, LQ / BM, BATCH), 256, 0, stream>>>(P16, VT, ctx);
    } else {
        // Fallback: round-1 pipeline.
        bf16_t* VT = (bf16_t*)ws;
        vt_kernel<<<dim3(LV / 64, DIM / 32, BATCH), 256, 0, stream>>>(V, VT);
        gemm1_fb<<<dim3(LV / BN, LQ / BM, BATCH), 256, 0, stream>>>(Q, V, attn);
        softmax_fb<<<BATCH * LQ, 256, 0, stream>>>(attn);
        gemm2_fb<<<dim3(DIM / BN, LQ / BM, BATCH), 256, 0, stream>>>(attn, VT, ctx);
    }
}

// Round 3
// 1232.799 us; speedup vs baseline: 1.0271x; 1.0164x over previous
//
#include <hip/hip_runtime.h>

typedef __bf16 bf16_t;
typedef __attribute__((ext_vector_type(4))) __bf16 bf16x4;
typedef __attribute__((ext_vector_type(8))) __bf16 bf16x8;
typedef __attribute__((ext_vector_type(4))) float f32x4;

constexpr int BATCH = 16;
constexpr int LQ = 2048;
constexpr int LV = 2048;
constexpr int DIM = 1024;

constexpr int BM = 128, BN = 128, BK = 32;

// ---------------------------------------------------------------------------
// async global->LDS, 16 B per lane. LDS dest must be wave-uniform base + lane*16.
// ---------------------------------------------------------------------------
typedef __attribute__((address_space(1))) const unsigned int g_u32;
typedef __attribute__((address_space(3))) unsigned int l_u32;
__device__ __forceinline__ void glds16(const void* g, void* l) {
    __builtin_amdgcn_global_load_lds((g_u32*)g, (l_u32*)l, 16, 0, 0);
}

// ---------------------------------------------------------------------------
// prep: fp32 x -> hi = bf16(x), lo = bf16(x - hi)
// ---------------------------------------------------------------------------
__global__ __launch_bounds__(256)
void prep_kernel(const float4* __restrict__ src, bf16x4* __restrict__ hi,
                 bf16x4* __restrict__ lo, int n4) {
    int i = blockIdx.x * 256 + threadIdx.x;
    const int stride = gridDim.x * 256;
    for (; i < n4; i += stride) {
        const float4 x = src[i];
        const float xs[4] = {x.x, x.y, x.z, x.w};
        bf16x4 h, l;
#pragma unroll
        for (int e = 0; e < 4; ++e) {
            bf16_t hh = (bf16_t)xs[e];
            h[e] = hh;
            l[e] = (bf16_t)(xs[e] - (float)hh);
        }
        hi[i] = h;
        lo[i] = l;
    }
}

// ---------------------------------------------------------------------------
// V (B, LV, DIM) fp32 -> VT (B, DIM, LV) bf16.  64(k) x 32(d) tiles.
// ---------------------------------------------------------------------------
__global__ __launch_bounds__(256)
void vt_kernel(const float* __restrict__ V, bf16_t* __restrict__ VT) {
    __shared__ float tile[64][33];
    const int b  = blockIdx.z;
    const int k0 = blockIdx.x * 64;
    const int d0 = blockIdx.y * 32;
    const int tid = threadIdx.x;
    const float* Vb  = V  + (size_t)b * LV * DIM;
    bf16_t*      VTb = VT + (size_t)b * DIM * LV;

    const int r = tid >> 3;          // 0..31
    const int c = (tid & 7) * 4;     // 0..28
#pragma unroll
    for (int h = 0; h < 2; ++h) {
        const float4 x = *(const float4*)(Vb + (size_t)(k0 + r + h * 32) * DIM + d0 + c);
        tile[r + h * 32][c]     = x.x;
        tile[r + h * 32][c + 1] = x.y;
        tile[r + h * 32][c + 2] = x.z;
        tile[r + h * 32][c + 3] = x.w;
    }
    __syncthreads();
    const int dd = tid >> 3;         // 0..31
    const int kk = (tid & 7) * 8;    // 0..56
    bf16x8 o;
#pragma unroll
    for (int j = 0; j < 8; ++j) o[j] = (bf16_t)tile[kk + j][dd];
    *(bf16x8*)&VTb[(size_t)(d0 + dd) * LV + k0 + kk] = o;
}

// ---------------------------------------------------------------------------
// GEMM1 v4: S = Q.V^T, 3-term split-bf16.
// 256x256 tile, BK=32, 8 waves (2Mx4N), double-buffered 128 KB dynamic LDS,
// 16B-chunk XOR swizzle (0 conflicts, verified r1).
// v4 = the guide's verified minimum-2-phase template (T3, m230/m248):
//   per K-step: { STAGE(next tile) ; ALL 24 ds_reads (two A reg-sets) ;
//                 96 MFMAs ; vmcnt(0) ; ONE barrier }
// STAGE's HBM latency hides under the ~3.7k-cyc MFMA cluster (vmcnt(0) at
// END, not before compute); all fragment reads issue up front so the only
// lgkm stall is the initial ramp (v3 had a dead 8-read pocket mid-region:
// LDS and MFMA phases serialized -> 7.6k cyc/K-step vs 3.7k MFMA floor).
// ---------------------------------------------------------------------------
__global__ __launch_bounds__(512, 2)
void gemm1_v4(const bf16_t* __restrict__ Qh, const bf16_t* __restrict__ Ql,
              const bf16_t* __restrict__ Vh, const bf16_t* __restrict__ Vl,
              float* __restrict__ S) {
    extern __shared__ __align__(16) char smem[];
    bf16_t* lds = (bf16_t*)smem;   // [2 bufs][4 arrays: Ah Al Bh Bl][256][32]

    const int b  = blockIdx.z;
    const int m0 = blockIdx.y * 256;
    const int n0 = blockIdx.x * 256;
    const bf16_t* Qhb = Qh + (size_t)b * LQ * DIM;
    const bf16_t* Qlb = Ql + (size_t)b * LQ * DIM;
    const bf16_t* Vhb = Vh + (size_t)b * LV * DIM;
    const bf16_t* Vlb = Vl + (size_t)b * LV * DIM;
    float*        Sb  = S  + (size_t)b * LQ * LV;

    const int tid  = threadIdx.x;
    const int lane = tid & 63;
    const int wave = tid >> 6;
    const int wm   = (wave >> 2) * 128;   // 2 M-halves
    const int wn   = (wave & 3) * 64;     // 4 N-quarters
    const int l15  = lane & 15;
    const int quad = lane >> 4;
    const int swz  = (l15 >> 1) & 3;          // = (row>>1)&3 for row = 16*i + l15
    const int rq   = (quad ^ swz) * 8;        // swizzled k-chunk (elems)

    // staging: thread tid covers LDS chunk (row = tid>>2, chunk = tid&3) of a
    // 128-row half; source k-chunk is inverse-swizzled so the swizzled read
    // finds global chunk `quad` at LDS chunk quad^swz.
    const int srow = tid >> 2;                              // 0..127
    const int sseg = (((tid & 3) ^ ((tid >> 3) & 3)) * 8);  // elems
    const int sdst = tid * 8;                               // elems (= byte tid*16)

#define STAGE8(BUF, K0) do {                                                        \
    bf16_t* Lb = lds + (BUF) * 32768;                                               \
    glds16(Qhb + (size_t)(m0 + srow      ) * DIM + (K0) + sseg, Lb +         sdst); \
    glds16(Qhb + (size_t)(m0 + srow + 128) * DIM + (K0) + sseg, Lb +  4096 + sdst); \
    glds16(Qlb + (size_t)(m0 + srow      ) * DIM + (K0) + sseg, Lb +  8192 + sdst); \
    glds16(Qlb + (size_t)(m0 + srow + 128) * DIM + (K0) + sseg, Lb + 12288 + sdst); \
    glds16(Vhb + (size_t)(n0 + srow      ) * DIM + (K0) + sseg, Lb + 16384 + sdst); \
    glds16(Vhb + (size_t)(n0 + srow + 128) * DIM + (K0) + sseg, Lb + 20480 + sdst); \
    glds16(Vlb + (size_t)(n0 + srow      ) * DIM + (K0) + sseg, Lb + 24576 + sdst); \
    glds16(Vlb + (size_t)(n0 + srow + 128) * DIM + (K0) + sseg, Lb + 28672 + sdst); \
} while (0)

#define LOADA(AH, AL, QI) do {                                               \
    _Pragma("unroll")                                                        \
    for (int ii = 0; ii < 4; ++ii) {                                         \
        const int row = wm + ((QI) * 4 + ii) * 16 + l15;                     \
        AH[ii] = *(const bf16x8*)(bufp +        row * 32 + rq);              \
        AL[ii] = *(const bf16x8*)(bufp + 8192 + row * 32 + rq);              \
    }                                                                        \
} while (0)

#define LOADB(QJ) do {                                                       \
    _Pragma("unroll")                                                        \
    for (int jj = 0; jj < 2; ++jj) {                                         \
        const int row = wn + ((QJ) * 2 + jj) * 16 + l15;                     \
        bh[(QJ) * 2 + jj] = *(const bf16x8*)(bufp + 16384 + row * 32 + rq);  \
        bl[(QJ) * 2 + jj] = *(const bf16x8*)(bufp + 24576 + row * 32 + rq);  \
    }                                                                        \
} while (0)

#define MFMAQ(AH, AL, QI, QJ) do {                                           \
    _Pragma("unroll")                                                        \
    for (int ii = 0; ii < 4; ++ii)                                           \
    _Pragma("unroll")                                                        \
    for (int jj = 0; jj < 2; ++jj)                                           \
        acc[(QI)*4+ii][(QJ)*2+jj] = __builtin_amdgcn_mfma_f32_16x16x32_bf16( \
            AH[ii], bh[(QJ)*2+jj], acc[(QI)*4+ii][(QJ)*2+jj], 0, 0, 0);      \
    _Pragma("unroll")                                                        \
    for (int ii = 0; ii < 4; ++ii)                                           \
    _Pragma("unroll")                                                        \
    for (int jj = 0; jj < 2; ++jj)                                           \
        acc[(QI)*4+ii][(QJ)*2+jj] = __builtin_amdgcn_mfma_f32_16x16x32_bf16( \
            AH[ii], bl[(QJ)*2+jj], acc[(QI)*4+ii][(QJ)*2+jj], 0, 0, 0);      \
    _Pragma("unroll")                                                        \
    for (int ii = 0; ii < 4; ++ii)                                           \
    _Pragma("unroll")                                                        \
    for (int jj = 0; jj < 2; ++jj)                                           \
        acc[(QI)*4+ii][(QJ)*2+jj] = __builtin_amdgcn_mfma_f32_16x16x32_bf16( \
            AL[ii], bh[(QJ)*2+jj], acc[(QI)*4+ii][(QJ)*2+jj], 0, 0, 0);      \
} while (0)

    f32x4 acc[8][4];
#pragma unroll
    for (int i = 0; i < 8; ++i)
#pragma unroll
        for (int j = 0; j < 4; ++j) {
            f32x4 z = {0.f, 0.f, 0.f, 0.f};
            acc[i][j] = z;
        }

    // Two A register sets so all 24 K-step reads issue before the MFMAs.
    bf16x8 a0h[4], a0l[4], a1h[4], a1l[4], bh[4], bl[4];

    // prologue: stage tile 0 into buf 0, drain, sync.
    STAGE8(0, 0);
    asm volatile("s_waitcnt vmcnt(0)" ::: "memory");
    __builtin_amdgcn_s_barrier();

    for (int t = 0; t < 32; ++t) {
        const bf16_t* bufp = lds + (t & 1) * 32768;

        // issue next tile's staging first: HBM latency hides under this
        // K-step's MFMA cluster; completion enforced by vmcnt(0) at the END.
        if (t < 31) STAGE8((t & 1) ^ 1, (t + 1) * 32);

        // all fragment reads up front; compiler's fine-grained lgkmcnt lets
        // later reads stay outstanding under the first MFMA cluster.
        LOADA(a0h, a0l, 0); LOADB(0); LOADB(1); LOADA(a1h, a1l, 1);

        __builtin_amdgcn_s_setprio(1);
        MFMAQ(a0h, a0l, 0, 0); MFMAQ(a0h, a0l, 0, 1);
        MFMAQ(a1h, a1l, 1, 0); MFMAQ(a1h, a1l, 1, 1);
        __builtin_amdgcn_s_setprio(0);

        // next-tile loads are now ~4k cycles old: this drain is near-free.
        asm volatile("s_waitcnt vmcnt(0)" ::: "memory");
        __builtin_amdgcn_s_barrier();   // one barrier per K-step
    }

#pragma unroll
    for (int i = 0; i < 8; ++i)
#pragma unroll
        for (int j = 0; j < 4; ++j)
#pragma unroll
            for (int r = 0; r < 4; ++r) {
                const int row = m0 + wm + i * 16 + quad * 4 + r;
                const int col = n0 + wn + j * 16 + l15;
                Sb[(size_t)row * LV + col] = acc[i][j][r];
            }

#undef STAGE8
#undef LOADA
#undef LOADB
#undef MFMAQ
}

// ---------------------------------------------------------------------------
// softmax (in-place fp32) + bf16 side copy for GEMM2
// ---------------------------------------------------------------------------
__global__ __launch_bounds__(256)
void softmax_b16(float* __restrict__ S, bf16_t* __restrict__ S16) {
    __shared__ float red[8];
    const size_t row = blockIdx.x;
    float* p = S + row * (size_t)LV;
    bf16_t* p16 = S16 + row * (size_t)LV;
    const int tid  = threadIdx.x;
    const int lane = tid & 63;
    const int wave = tid >> 6;

    float4 v0 = ((const float4*)p)[tid];
    float4 v1 = ((const float4*)p)[tid + 256];

    float m = fmaxf(fmaxf(fmaxf(v0.x, v0.y), fmaxf(v0.z, v0.w)),
                    fmaxf(fmaxf(v1.x, v1.y), fmaxf(v1.z, v1.w)));
#pragma unroll
    for (int off = 32; off > 0; off >>= 1) m = fmaxf(m, __shfl_xor(m, off));
    if (lane == 0) red[wave] = m;
    __syncthreads();
    m = fmaxf(fmaxf(red[0], red[1]), fmaxf(red[2], red[3]));

    float e0 = __expf(v0.x - m), e1 = __expf(v0.y - m);
    float e2 = __expf(v0.z - m), e3 = __expf(v0.w - m);
    float e4 = __expf(v1.x - m), e5 = __expf(v1.y - m);
    float e6 = __expf(v1.z - m), e7 = __expf(v1.w - m);

    float s = ((e0 + e1) + (e2 + e3)) + ((e4 + e5) + (e6 + e7));
#pragma unroll
    for (int off = 32; off > 0; off >>= 1) s += __shfl_xor(s, off);
    if (lane == 0) red[4 + wave] = s;
    __syncthreads();
    s = (red[4] + red[5]) + (red[6] + red[7]);

    const float inv = 1.0f / s;
    v0.x = e0 * inv; v0.y = e1 * inv; v0.z = e2 * inv; v0.w = e3 * inv;
    v1.x = e4 * inv; v1.y = e5 * inv; v1.z = e6 * inv; v1.w = e7 * inv;
    ((float4*)p)[tid]       = v0;
    ((float4*)p)[tid + 256] = v1;

    bf16x4 h0, h1;
    h0[0] = (bf16_t)v0.x; h0[1] = (bf16_t)v0.y; h0[2] = (bf16_t)v0.z; h0[3] = (bf16_t)v0.w;
    h1[0] = (bf16_t)v1.x; h1[1] = (bf16_t)v1.y; h1[2] = (bf16_t)v1.z; h1[3] = (bf16_t)v1.w;
    ((bf16x4*)p16)[tid]       = h0;
    ((bf16x4*)p16)[tid + 256] = h1;
}

// ---------------------------------------------------------------------------
// GEMM2 (glds): context = attn_bf16 . VT^T
// ---------------------------------------------------------------------------
__global__ __launch_bounds__(256, 3)
void gemm2_glds(const bf16_t* __restrict__ P16, const bf16_t* __restrict__ VT,
                float* __restrict__ C) {
    __shared__ __align__(16) bf16_t As[BM][BK];
    __shared__ __align__(16) bf16_t Bs[BN][BK];

    const int b  = blockIdx.z;
    const int m0 = blockIdx.y * BM;   // q
    const int n0 = blockIdx.x * BN;   // d
    const bf16_t* Pb = P16 + (size_t)b * LQ * LV;
    const bf16_t* Vb = VT  + (size_t)b * DIM * LV;
    float*        Cb = C   + (size_t)b * LQ * DIM;

    const int tid  = threadIdx.x;
    const int lane = tid & 63;
    const int wave = tid >> 6;
    const int wm   = (wave >> 1) * 64;
    const int wn   = (wave & 1) * 64;
    const int l15  = lane & 15;
    const int quad = lane >> 4;

    const int srow = tid >> 2;
    const int sseg = (tid & 3) * 8;

    f32x4 acc[4][4];
#pragma unroll
    for (int i = 0; i < 4; ++i)
#pragma unroll
        for (int j = 0; j < 4; ++j) {
            f32x4 z = {0.f, 0.f, 0.f, 0.f};
            acc[i][j] = z;
        }

    for (int k0 = 0; k0 < LV; k0 += BK) {
        glds16(Pb + (size_t)(m0 + srow) * LV + k0 + sseg,      &As[srow][sseg]);
        glds16(Pb + (size_t)(m0 + srow + 64) * LV + k0 + sseg, &As[srow + 64][sseg]);
        glds16(Vb + (size_t)(n0 + srow) * LV + k0 + sseg,      &Bs[srow][sseg]);
        glds16(Vb + (size_t)(n0 + srow + 64) * LV + k0 + sseg, &Bs[srow + 64][sseg]);
        __syncthreads();

        bf16x8 af[4], bfr[4];
#pragma unroll
        for (int i = 0; i < 4; ++i) {
            af[i]  = *(const bf16x8*)&As[wm + i * 16 + l15][quad * 8];
            bfr[i] = *(const bf16x8*)&Bs[wn + i * 16 + l15][quad * 8];
        }
#pragma unroll
        for (int i = 0; i < 4; ++i)
#pragma unroll
            for (int j = 0; j < 4; ++j)
                acc[i][j] = __builtin_amdgcn_mfma_f32_16x16x32_bf16(af[i], bfr[j], acc[i][j], 0, 0, 0);
        __syncthreads();
    }

#pragma unroll
    for (int i = 0; i < 4; ++i)
#pragma unroll
        for (int j = 0; j < 4; ++j)
#pragma unroll
            for (int r = 0; r < 4; ++r) {
                const int row = m0 + wm + i * 16 + quad * 4 + r;
                const int col = n0 + wn + j * 16 + l15;
                Cb[(size_t)row * DIM + col] = acc[i][j][r];
            }
}

// ===========================================================================
// Fallback tier (round-1 proven kernels) in case ws is too small.
// ===========================================================================
__global__ __launch_bounds__(256, 2)
void gemm1_fb(const float* __restrict__ Q, const float* __restrict__ V,
              float* __restrict__ S) {
    __shared__ __align__(16) bf16_t Ahi[BM][BK];
    __shared__ __align__(16) bf16_t Alo[BM][BK];
    __shared__ __align__(16) bf16_t Bhi[BN][BK];
    __shared__ __align__(16) bf16_t Blo[BN][BK];

    const int b  = blockIdx.z;
    const int m0 = blockIdx.y * BM;
    const int n0 = blockIdx.x * BN;
    const float* Qb = Q + (size_t)b * LQ * DIM;
    const float* Vb = V + (size_t)b * LV * DIM;
    float*       Sb = S + (size_t)b * LQ * LV;

    const int tid  = threadIdx.x;
    const int lane = tid & 63;
    const int wave = tid >> 6;
    const int wm   = (wave >> 1) * 64;
    const int wn   = (wave & 1) * 64;
    const int l15  = lane & 15;
    const int quad = lane >> 4;
    const int srow = tid >> 3;
    const int scol = (tid & 7) * 4;

    f32x4 acc[4][4];
#pragma unroll
    for (int i = 0; i < 4; ++i)
#pragma unroll
        for (int j = 0; j < 4; ++j) {
            f32x4 z = {0.f, 0.f, 0.f, 0.f};
            acc[i][j] = z;
        }

    for (int k0 = 0; k0 < DIM; k0 += BK) {
#pragma unroll
        for (int p = 0; p < 4; ++p) {
            const int r = p * 32 + srow;
            const float4 qa = *(const float4*)(Qb + (size_t)(m0 + r) * DIM + k0 + scol);
            const float4 va = *(const float4*)(Vb + (size_t)(n0 + r) * DIM + k0 + scol);
            const float qx[4] = {qa.x, qa.y, qa.z, qa.w};
            const float vx[4] = {va.x, va.y, va.z, va.w};
            bf16x4 qh, ql, vh, vl;
#pragma unroll
            for (int e = 0; e < 4; ++e) {
                bf16_t h = (bf16_t)qx[e];
                qh[e] = h; ql[e] = (bf16_t)(qx[e] - (float)h);
                bf16_t h2 = (bf16_t)vx[e];
                vh[e] = h2; vl[e] = (bf16_t)(vx[e] - (float)h2);
            }
            *(bf16x4*)&Ahi[r][scol] = qh;
            *(bf16x4*)&Alo[r][scol] = ql;
            *(bf16x4*)&Bhi[r][scol] = vh;
            *(bf16x4*)&Blo[r][scol] = vl;
        }
        __syncthreads();
        bf16x8 ah[4], al[4], bh[4], bl[4];
#pragma unroll
        for (int i = 0; i < 4; ++i) {
            ah[i] = *(const bf16x8*)&Ahi[wm + i * 16 + l15][quad * 8];
            al[i] = *(const bf16x8*)&Alo[wm + i * 16 + l15][quad * 8];
            bh[i] = *(const bf16x8*)&Bhi[wn + i * 16 + l15][quad * 8];
            bl[i] = *(const bf16x8*)&Blo[wn + i * 16 + l15][quad * 8];
        }
#pragma unroll
        for (int i = 0; i < 4; ++i)
#pragma unroll
            for (int j = 0; j < 4; ++j) {
                acc[i][j] = __builtin_amdgcn_mfma_f32_16x16x32_bf16(ah[i], bh[j], acc[i][j], 0, 0, 0);
                acc[i][j] = __builtin_amdgcn_mfma_f32_16x16x32_bf16(ah[i], bl[j], acc[i][j], 0, 0, 0);
                acc[i][j] = __builtin_amdgcn_mfma_f32_16x16x32_bf16(al[i], bh[j], acc[i][j], 0, 0, 0);
            }
        __syncthreads();
    }
#pragma unroll
    for (int i = 0; i < 4; ++i)
#pragma unroll
        for (int j = 0; j < 4; ++j)
#pragma unroll
            for (int r = 0; r < 4; ++r) {
                const int row = m0 + wm + i * 16 + quad * 4 + r;
                const int col = n0 + wn + j * 16 + l15;
                Sb[(size_t)row * LV + col] = acc[i][j][r];
            }
}

__global__ __launch_bounds__(256)
void softmax_fb(float* __restrict__ S) {
    __shared__ float red[8];
    const size_t row = blockIdx.x;
    float* p = S + row * (size_t)LV;
    const int tid  = threadIdx.x;
    const int lane = tid & 63;
    const int wave = tid >> 6;
    float4 v0 = ((const float4*)p)[tid];
    float4 v1 = ((const float4*)p)[tid + 256];
    float m = fmaxf(fmaxf(fmaxf(v0.x, v0.y), fmaxf(v0.z, v0.w)),
                    fmaxf(fmaxf(v1.x, v1.y), fmaxf(v1.z, v1.w)));
#pragma unroll
    for (int off = 32; off > 0; off >>= 1) m = fmaxf(m, __shfl_xor(m, off));
    if (lane == 0) red[wave] = m;
    __syncthreads();
    m = fmaxf(fmaxf(red[0], red[1]), fmaxf(red[2], red[3]));
    float e0 = __expf(v0.x - m), e1 = __expf(v0.y - m);
    float e2 = __expf(v0.z - m), e3 = __expf(v0.w - m);
    float e4 = __expf(v1.x - m), e5 = __expf(v1.y - m);
    float e6 = __expf(v1.z - m), e7 = __expf(v1.w - m);
    float s = ((e0 + e1) + (e2 + e3)) + ((e4 + e5) + (e6 + e7));
#pragma unroll
    for (int off = 32; off > 0; off >>= 1) s += __shfl_xor(s, off);
    if (lane == 0) red[4 + wave] = s;
    __syncthreads();
    s = (red[4] + red[5]) + (red[6] + red[7]);
    const float inv = 1.0f / s;
    v0.x = e0 * inv; v0.y = e1 * inv; v0.z = e2 * inv; v0.w = e3 * inv;
    v1.x = e4 * inv; v1.y = e5 * inv; v1.z = e6 * inv; v1.w = e7 * inv;
    ((float4*)p)[tid]       = v0;
    ((float4*)p)[tid + 256] = v1;
}

__global__ __launch_bounds__(256, 2)
void gemm2_fb(const float* __restrict__ P, const bf16_t* __restrict__ VT,
              float* __restrict__ C) {
    __shared__ __align__(16) bf16_t As[BM][BK];
    __shared__ __align__(16) bf16_t Bs[BN][BK];
    const int b  = blockIdx.z;
    const int m0 = blockIdx.y * BM;
    const int n0 = blockIdx.x * BN;
    const float*  Pb = P  + (size_t)b * LQ * LV;
    const bf16_t* Vb = VT + (size_t)b * DIM * LV;
    float*        Cb = C  + (size_t)b * LQ * DIM;
    const int tid  = threadIdx.x;
    const int lane = tid & 63;
    const int wave = tid >> 6;
    const int wm   = (wave >> 1) * 64;
    const int wn   = (wave & 1) * 64;
    const int l15  = lane & 15;
    const int quad = lane >> 4;
    const int arow = tid >> 3;
    const int acol = (tid & 7) * 4;
    const int brow = tid >> 2;
    const int bseg = (tid & 3) * 8;
    f32x4 acc[4][4];
#pragma unroll
    for (int i = 0; i < 4; ++i)
#pragma unroll
        for (int j = 0; j < 4; ++j) {
            f32x4 z = {0.f, 0.f, 0.f, 0.f};
            acc[i][j] = z;
        }
    for (int k0 = 0; k0 < LV; k0 += BK) {
#pragma unroll
        for (int p4 = 0; p4 < 4; ++p4) {
            const int r = p4 * 32 + arow;
            const float4 a = *(const float4*)(Pb + (size_t)(m0 + r) * LV + k0 + acol);
            bf16x4 hv;
            hv[0] = (bf16_t)a.x; hv[1] = (bf16_t)a.y;
            hv[2] = (bf16_t)a.z; hv[3] = (bf16_t)a.w;
            *(bf16x4*)&As[r][acol] = hv;
        }
#pragma unroll
        for (int p4 = 0; p4 < 2; ++p4) {
            const int r = p4 * 64 + brow;
            *(bf16x8*)&Bs[r][bseg] =
                *(const bf16x8*)(Vb + (size_t)(n0 + r) * LV + k0 + bseg);
        }
        __syncthreads();
        bf16x8 af[4], bfr[4];
#pragma unroll
        for (int i = 0; i < 4; ++i) {
            af[i]  = *(const bf16x8*)&As[wm + i * 16 + l15][quad * 8];
            bfr[i] = *(const bf16x8*)&Bs[wn + i * 16 + l15][quad * 8];
        }
#pragma unroll
        for (int i = 0; i < 4; ++i)
#pragma unroll
            for (int j = 0; j < 4; ++j)
                acc[i][j] = __builtin_amdgcn_mfma_f32_16x16x32_bf16(af[i], bfr[j], acc[i][j], 0, 0, 0);
        __syncthreads();
    }
#pragma unroll
    for (int i = 0; i < 4; ++i)
#pragma unroll
        for (int j = 0; j < 4; ++j)
#pragma unroll
            for (int r = 0; r < 4; ++r) {
                const int row = m0 + wm + i * 16 + quad * 4 + r;
                const int col = n0 + wn + j * 16 + l15;
                Cb[(size_t)row * DIM + col] = acc[i][j][r];
            }
}

// ---------------------------------------------------------------------------
extern "C" void kernel_launch(void* const* d_in, const int* in_sizes, int n_in,
                              void* d_out, int out_size, void* d_ws, size_t ws_size,
                              hipStream_t stream) {
    const float* Q = (const float*)d_in[0];
    const float* V = (const float*)d_in[1];
    float* ctx  = (float*)d_out;                       // B*LQ*DIM fp32
    float* attn = ctx + (size_t)BATCH * LQ * DIM;      // B*LQ*LV fp32
    char* ws = (char*)d_ws;

    const size_t EL = (size_t)BATCH * LQ * DIM;        // 33,554,432 elems
    const size_t SZ = EL * sizeof(bf16_t);             // 67,108,864 B

    if (ws_size >= 5 * SZ) {
        // Full tier: prep split + single-barrier pipelined 256^2 gemm1 + glds gemm2.
        static bool attr_set = false;
        if (!attr_set) {
            (void)hipFuncSetAttribute((const void*)gemm1_v4,
                                      hipFuncAttributeMaxDynamicSharedMemorySize,
                                      131072);
            attr_set = true;
        }
        bf16_t* Qh  = (bf16_t*)ws;
        bf16_t* Ql  = Qh + EL;
        bf16_t* Vh  = Ql + EL;
        bf16_t* Vl  = Vh + EL;
        bf16_t* VT  = (bf16_t*)(ws + 4 * SZ);
        bf16_t* P16 = (bf16_t*)ws;                     // aliases Qh/Ql after gemm1

        prep_kernel<<<4096, 256, 0, stream>>>((const float4*)Q, (bf16x4*)Qh, (bf16x4*)Ql, (int)(EL / 4));
        prep_kernel<<<4096, 256, 0, stream>>>((const float4*)V, (bf16x4*)Vh, (bf16x4*)Vl, (int)(EL / 4));
        vt_kernel<<<dim3(LV / 64, DIM / 32, BATCH), 256, 0, stream>>>(V, VT);
        gemm1_v4<<<dim3(LV / 256, LQ / 256, BATCH), 512, 131072, stream>>>(Qh, Ql, Vh, Vl, attn);
        softmax_b16<<<BATCH * LQ, 256, 0, stream>>>(attn, P16);
        gemm2_glds<<<dim3(DIM / BN, LQ / BM, BATCH), 256, 0, stream>>>(P16, VT, ctx);
    } else if (ws_size >= 3 * SZ) {
        // Mid tier: old gemm1, glds gemm2.
        bf16_t* VT  = (bf16_t*)ws;
        bf16_t* P16 = (bf16_t*)(ws + SZ);
        vt_kernel<<<dim3(LV / 64, DIM / 32, BATCH), 256, 0, stream>>>(V, VT);
        gemm1_fb<<<dim3(LV / BN, LQ / BM, BATCH), 256, 0, stream>>>(Q, V, attn);
        softmax_b16<<<BATCH * LQ, 256, 0, stream>>>(attn, P16);
        gemm2_glds<<<dim3(DIM / BN, LQ / BM, BATCH), 256, 0, stream>>>(P16, VT, ctx);
    } else {
        // Fallback: round-1 pipeline.
        bf16_t* VT = (bf16_t*)ws;
        vt_kernel<<<dim3(LV / 64, DIM / 32, BATCH), 256, 0, stream>>>(V, VT);
        gemm1_fb<<<dim3(LV / BN, LQ / BM, BATCH), 256, 0, stream>>>(Q, V, attn);
        softmax_fb<<<BATCH * LQ, 256, 0, stream>>>(attn);
        gemm2_fb<<<dim3(DIM / BN, LQ / BM, BATCH), 256, 0, stream>>>(attn, VT, ctx);
    }
}